// Round 11
// baseline (266.065 us; speedup 1.0000x reference)
//
#include <hip/hip_runtime.h>
#include <hip/hip_bf16.h>

typedef __attribute__((ext_vector_type(8))) __bf16 bf16x8;
typedef __attribute__((ext_vector_type(4))) __bf16 bf16x4;
typedef __attribute__((ext_vector_type(4))) float f32x4;

#define N_TOK 8192
#define IN_FEAT 2048
#define D1 512
#define D2 128
#define QBLK 128
#define KCHUNK 1024
#define KTILE 128
#define NKC (N_TOK / KCHUNK)   // 8
#define NQB (N_TOK / QBLK)     // 64
#define LOG2E 1.44269504f

__device__ __forceinline__ float fexp2(float x) {
    float r;
    asm("v_exp_f32 %0, %1" : "=v"(r) : "v"(x));
    return r;
}

__device__ __forceinline__ void gload_lds16(const __bf16* g, __bf16* l) {
    __builtin_amdgcn_global_load_lds(
        (const __attribute__((address_space(1))) void*)g,
        (__attribute__((address_space(3))) void*)l,
        16, 0, 0);
}

// ---------------------------------------------------------------------------
// prep: fused weight casts + wksum + xw/xh zero (one launch)
// ---------------------------------------------------------------------------
__global__ __launch_bounds__(256)
void prep(const float* __restrict__ W1, __bf16* __restrict__ w1b,
          const float* __restrict__ W2, __bf16* __restrict__ w2b,
          const float* __restrict__ Wq, __bf16* __restrict__ wqb,
          const float* __restrict__ Wk, float* __restrict__ wksum,
          float* __restrict__ xw, float* __restrict__ xh) {
    int b = blockIdx.x, t = threadIdx.x;
    const float* src = nullptr; __bf16* dst = nullptr; int i = 0;
    if (b < 1024)      { src = W1; dst = w1b; i = b * 256 + t; }
    else if (b < 1088) { src = W2; dst = w2b; i = (b - 1024) * 256 + t; }
    else if (b < 1104) { src = Wq; dst = wqb; i = (b - 1088) * 256 + t; }
    else {
        if (t < D2) {
            float s = 0.0f;
            for (int o = 0; o < D2; ++o) s += Wk[o * D2 + t];
            wksum[t] = s;
            xw[t] = 0.0f; xh[t] = 0.0f;
        }
        return;
    }
    float4 v = ((const float4*)src)[i];
    bf16x4 o;
    o[0] = (__bf16)v.x; o[1] = (__bf16)v.y; o[2] = (__bf16)v.z; o[3] = (__bf16)v.w;
    ((bf16x4*)dst)[i] = o;
}

// ---------------------------------------------------------------------------
// gemm1: h1 = relu(x @ W1^T + b1). A f32 reg-staged + prefetch. BM=128 BN=64.
// 1D grid 512; decode y=b&63, x=b>>6 -> XCD-shared x-strip (T1).
// ---------------------------------------------------------------------------
__global__ __launch_bounds__(256)
void gemm1_k(const float* __restrict__ x, const __bf16* __restrict__ w1b,
             const float* __restrict__ b1, __bf16* __restrict__ h1b) {
    __shared__ __bf16 lA[128 * 32];
    __shared__ __bf16 lB[64 * 32];

    const int t    = threadIdx.x;
    const int lane = t & 63;
    const int w    = t >> 6;
    const int wr   = w >> 1;
    const int wc   = w & 1;
    const int b    = blockIdx.x;
    const int m0   = (b & 63) * 128;
    const int n0   = (b >> 6) * 64;

    const int rS = w * 16 + (lane >> 2);
    const int cS = (lane & 3) * 8;
    const int fr = lane & 15;
    const int hi = lane >> 4;
    const int ko = hi * 8;
    const int rj = hi * 4;

    const int ar = t >> 3;
    const int ac = (t & 7) * 4;

    f32x4 acc[4][2] = {};

    float4 regs[4];
#pragma unroll
    for (int i = 0; i < 4; ++i)
        regs[i] = *(const float4*)&x[(size_t)(m0 + i * 32 + ar) * IN_FEAT + ac];

    for (int k0 = 0; k0 < IN_FEAT; k0 += 32) {
        __syncthreads();
#pragma unroll
        for (int i = 0; i < 4; ++i) {
            bf16x4 o;
            o[0] = (__bf16)regs[i].x; o[1] = (__bf16)regs[i].y;
            o[2] = (__bf16)regs[i].z; o[3] = (__bf16)regs[i].w;
            *(bf16x4*)&lA[(i * 32 + ar) * 32 + ac] = o;
        }
        gload_lds16(w1b + (size_t)(n0 + rS) * IN_FEAT + k0 + cS, lB + w * 512);
        __syncthreads();

        if (k0 + 32 < IN_FEAT) {
#pragma unroll
            for (int i = 0; i < 4; ++i)
                regs[i] = *(const float4*)&x[(size_t)(m0 + i * 32 + ar) * IN_FEAT + k0 + 32 + ac];
        }

        bf16x8 af[4], bf[2];
#pragma unroll
        for (int m = 0; m < 4; ++m)
            af[m] = *(const bf16x8*)&lA[(wr * 64 + m * 16 + fr) * 32 + ko];
#pragma unroll
        for (int n = 0; n < 2; ++n)
            bf[n] = *(const bf16x8*)&lB[(wc * 32 + n * 16 + fr) * 32 + ko];
#pragma unroll
        for (int m = 0; m < 4; ++m)
#pragma unroll
            for (int n = 0; n < 2; ++n)
                acc[m][n] = __builtin_amdgcn_mfma_f32_16x16x32_bf16(af[m], bf[n], acc[m][n], 0, 0, 0);
    }

#pragma unroll
    for (int n = 0; n < 2; ++n) {
        int col = n0 + wc * 32 + n * 16 + fr;
        float bv = b1[col];
#pragma unroll
        for (int m = 0; m < 4; ++m) {
            int row = m0 + wr * 64 + m * 16 + rj;
#pragma unroll
            for (int j = 0; j < 4; ++j)
                h1b[(size_t)(row + j) * D1 + col] = (__bf16)fmaxf(acc[m][n][j] + bv, 0.0f);
        }
    }
}

// ---------------------------------------------------------------------------
// mlp2: per 32-row block: h2 = relu(h1 @ W2^T + b2) -> h2b, kb (col-scale),
// q = (h2 @ Wq^T + bq) * LOG2E -> qb  (base-2 softmax domain).
// ---------------------------------------------------------------------------
__global__ __launch_bounds__(256)
void mlp2_k(const __bf16* __restrict__ h1b, const __bf16* __restrict__ w2b,
            const float* __restrict__ b2, const __bf16* __restrict__ wqb,
            const float* __restrict__ bq, const float* __restrict__ wksum,
            const float* __restrict__ bk, __bf16* __restrict__ h2b,
            __bf16* __restrict__ kb, __bf16* __restrict__ qb) {
    __shared__ __bf16 lA[32 * 32];
    __shared__ __bf16 lB[128 * 32];
    __shared__ __bf16 lH[32 * 128];

    const int t    = threadIdx.x;
    const int lane = t & 63;
    const int w    = t >> 6;
    const int fr   = lane & 15;
    const int hi   = lane >> 4;
    const int ko   = hi * 8;
    const int m0   = blockIdx.x * 32;

    f32x4 acc[2][2] = {};

    for (int k0 = 0; k0 < D1; k0 += 32) {
        __syncthreads();
        if (w < 2)
            gload_lds16(h1b + (size_t)(m0 + w * 16 + (lane >> 2)) * D1 + k0 + (lane & 3) * 8,
                        lA + w * 512);
#pragma unroll
        for (int i = 0; i < 2; ++i) {
            int row = w * 32 + i * 16 + (lane >> 2);
            gload_lds16(w2b + (size_t)row * D1 + k0 + (lane & 3) * 8,
                        lB + w * 1024 + i * 512);
        }
        __syncthreads();

        bf16x8 af[2], bf[2];
#pragma unroll
        for (int m = 0; m < 2; ++m)
            af[m] = *(const bf16x8*)&lA[(m * 16 + fr) * 32 + ko];
#pragma unroll
        for (int n = 0; n < 2; ++n)
            bf[n] = *(const bf16x8*)&lB[(w * 32 + n * 16 + fr) * 32 + ko];
#pragma unroll
        for (int m = 0; m < 2; ++m)
#pragma unroll
            for (int n = 0; n < 2; ++n)
                acc[m][n] = __builtin_amdgcn_mfma_f32_16x16x32_bf16(af[m], bf[n], acc[m][n], 0, 0, 0);
    }

#pragma unroll
    for (int n = 0; n < 2; ++n) {
        int col = w * 32 + n * 16 + fr;
        float bv = b2[col], wv = wksum[col], bkv = bk[col];
#pragma unroll
        for (int m = 0; m < 2; ++m) {
#pragma unroll
            for (int j = 0; j < 4; ++j) {
                int row = m * 16 + hi * 4 + j;
                float v = fmaxf(acc[m][n][j] + bv, 0.0f);
                h2b[(size_t)(m0 + row) * D2 + col] = (__bf16)v;
                kb [(size_t)(m0 + row) * D2 + col] = (__bf16)(wv * v + bkv);
                lH[row * 128 + (((col >> 3) ^ (row & 7)) * 8) + (col & 7)] = (__bf16)v;
            }
        }
    }
    __syncthreads();

    f32x4 acc2[2][2] = {};
#pragma unroll
    for (int kk = 0; kk < 4; ++kk) {
        bf16x8 af2[2], bf2[2];
#pragma unroll
        for (int m = 0; m < 2; ++m) {
            int row = m * 16 + fr;
            af2[m] = *(const bf16x8*)&lH[row * 128 + (((kk * 4 + hi) ^ (row & 7)) * 8)];
        }
#pragma unroll
        for (int n = 0; n < 2; ++n)
            bf2[n] = *(const bf16x8*)&wqb[(size_t)(w * 32 + n * 16 + fr) * D2 + kk * 32 + ko];
#pragma unroll
        for (int m = 0; m < 2; ++m)
#pragma unroll
            for (int n = 0; n < 2; ++n)
                acc2[m][n] = __builtin_amdgcn_mfma_f32_16x16x32_bf16(af2[m], bf2[n], acc2[m][n], 0, 0, 0);
    }
#pragma unroll
    for (int n = 0; n < 2; ++n) {
        int col = w * 32 + n * 16 + fr;
        float bv = bq[col];
#pragma unroll
        for (int m = 0; m < 2; ++m)
#pragma unroll
            for (int j = 0; j < 4; ++j) {
                int row = m0 + m * 16 + hi * 4 + j;
                qb[(size_t)row * D2 + col] = (__bf16)((acc2[m][n][j] + bv) * LOG2E);
            }
    }
}

// ---------------------------------------------------------------------------
// Fused attention — ROUND-7-VERBATIM math (defer-max online softmax, pm/pl,
// 1.0f/L combine), direct-L2 fragment loads, base-2 domain.
// SINGLE CHANGE vs round 7 (bisection): fa2's column sums accumulate in LDS
// lcol and flush to per-block colp[by] partials instead of global atomics.
// ---------------------------------------------------------------------------
template<int PASS>
__global__ __launch_bounds__(256, 2)
void fa_kernel(const __bf16* __restrict__ qbuf, const __bf16* __restrict__ kbuf,
               float* __restrict__ pm, float* __restrict__ pl,
               float* __restrict__ attn, float* __restrict__ colp)
{
    __shared__ float rowM_l[QBLK], rowInv_l[QBLK];
    __shared__ float lcol[KCHUNK];

    const int t    = threadIdx.x;
    const int lane = t & 63;
    const int w    = t >> 6;
    const int wr   = w >> 1;
    const int wc   = w & 1;
    const int fr   = lane & 15;
    const int hi   = lane >> 4;
    const int ck   = blockIdx.x;
    const int by   = blockIdx.y;
    const int q0   = by * QBLK;
    const int kr0  = ck * KCHUNK;

    // Q fragments straight from L2
    bf16x8 af[4][4];
#pragma unroll
    for (int m = 0; m < 4; ++m)
#pragma unroll
        for (int kk = 0; kk < 4; ++kk)
            af[m][kk] = *(const bf16x8*)&qbuf[(size_t)(q0 + wr * 64 + m * 16 + fr) * D2 + kk * 32 + hi * 8];

    float mloc[4][4], lloc[4][4], Mr[4][4], Ir[4][4];
    if constexpr (PASS == 2) {
        if (t < QBLK) {
            int r = q0 + t;
            float M = -1e30f;
#pragma unroll
            for (int c = 0; c < 2 * NKC; ++c) M = fmaxf(M, pm[(size_t)c * N_TOK + r]);
            float L = 0.0f;
#pragma unroll
            for (int c = 0; c < 2 * NKC; ++c)
                L += pl[(size_t)c * N_TOK + r] * fexp2(pm[(size_t)c * N_TOK + r] - M);
            rowM_l[t] = M;
            rowInv_l[t] = 1.0f / L;
        }
        for (int i = t; i < KCHUNK; i += 256) lcol[i] = 0.0f;
        __syncthreads();
#pragma unroll
        for (int m = 0; m < 4; ++m)
#pragma unroll
            for (int j = 0; j < 4; ++j) {
                int rl = wr * 64 + m * 16 + hi * 4 + j;
                Mr[m][j] = rowM_l[rl]; Ir[m][j] = rowInv_l[rl];
            }
    } else {
#pragma unroll
        for (int m = 0; m < 4; ++m)
#pragma unroll
            for (int j = 0; j < 4; ++j) { mloc[m][j] = -1e30f; lloc[m][j] = 0.0f; }
    }

    const __bf16* kbase = kbuf + (size_t)(kr0 + wc * 64 + fr) * D2 + hi * 8;

#pragma unroll 1
    for (int kt = 0; kt < KCHUNK / KTILE; ++kt) {
        const __bf16* kp = kbase + (size_t)kt * KTILE * D2;

        f32x4 acc[4][4] = {};
#pragma unroll
        for (int kk = 0; kk < 4; ++kk) {
            bf16x8 bfr[4];
#pragma unroll
            for (int n = 0; n < 4; ++n)
                bfr[n] = *(const bf16x8*)&kp[(size_t)n * 16 * D2 + kk * 32];
#pragma unroll
            for (int m = 0; m < 4; ++m)
#pragma unroll
                for (int n = 0; n < 4; ++n)
                    acc[m][n] = __builtin_amdgcn_mfma_f32_16x16x32_bf16(af[m][kk], bfr[n], acc[m][n], 0, 0, 0);
        }

        if constexpr (PASS == 1) {
#pragma unroll
            for (int m = 0; m < 4; ++m)
#pragma unroll
                for (int j = 0; j < 4; ++j) {
                    float a0 = acc[m][0][j], a1 = acc[m][1][j], a2 = acc[m][2][j], a3 = acc[m][3][j];
                    float t4 = fmaxf(fmaxf(a0, a1), fmaxf(a2, a3));
                    if (!__all(t4 <= mloc[m][j] + 11.5f)) {   // T13 defer-max
                        float mn = fmaxf(mloc[m][j], t4);
                        lloc[m][j] *= fexp2(mloc[m][j] - mn);
                        mloc[m][j] = mn;
                    }
                    float mo = mloc[m][j];
                    lloc[m][j] += fexp2(a0 - mo) + fexp2(a1 - mo) + fexp2(a2 - mo) + fexp2(a3 - mo);
                }
        } else {
            const int colb = kt * KTILE + wc * 64;   // chunk-local col base
            float csum[4] = {0.0f, 0.0f, 0.0f, 0.0f};
#pragma unroll
            for (int m = 0; m < 4; ++m) {
#pragma unroll
                for (int n = 0; n < 4; ++n) {
                    int col = kr0 + colb + n * 16 + fr;
#pragma unroll
                    for (int j = 0; j < 4; ++j) {
                        int row = q0 + wr * 64 + m * 16 + hi * 4 + j;
                        float p = fexp2(acc[m][n][j] - Mr[m][j]) * Ir[m][j];
                        attn[(size_t)row * N_TOK + col] = p;
                        csum[n] += p;
                    }
                }
            }
#pragma unroll
            for (int n = 0; n < 4; ++n) {
                csum[n] += __shfl_xor(csum[n], 16);
                csum[n] += __shfl_xor(csum[n], 32);
            }
            if (lane < 16) {
#pragma unroll
                for (int n = 0; n < 4; ++n)
                    atomicAdd(&lcol[colb + n * 16 + lane], csum[n]);
            }
        }
    }

    if constexpr (PASS == 1) {
        const size_t slot = (size_t)(ck * 2 + wc) * N_TOK;
#pragma unroll
        for (int m = 0; m < 4; ++m)
#pragma unroll
            for (int j = 0; j < 4; ++j) {
                float M = mloc[m][j];
#pragma unroll
                for (int off = 1; off <= 8; off <<= 1) M = fmaxf(M, __shfl_xor(M, off));
                float l = lloc[m][j] * fexp2(mloc[m][j] - M);
#pragma unroll
                for (int off = 1; off <= 8; off <<= 1) l += __shfl_xor(l, off);
                if ((lane & 15) == 0) {
                    int r = q0 + wr * 64 + m * 16 + hi * 4 + j;
                    pm[slot + r] = M;
                    pl[slot + r] = l;
                }
            }
    } else {
        __syncthreads();
        for (int i = t; i < KCHUNK; i += 256)
            colp[(size_t)by * N_TOK + kr0 + i] = lcol[i];
    }
}

// ---------------------------------------------------------------------------
// reduce_x2: colw[m] = sum_by colp[by][m] (LDS-staged), then
// xw[c] += sum_m colw[m]*h2[m,c] ; xh[c] += sum_m h2[m,c]
// ---------------------------------------------------------------------------
__global__ __launch_bounds__(256)
void reduce_x2(const __bf16* __restrict__ h2b, const float* __restrict__ colp,
               float* __restrict__ xw, float* __restrict__ xh) {
    __shared__ float part[256];
    __shared__ float lcolw[128];
    int b = blockIdx.x, t = threadIdx.x;
    int mi = t & 127, half = t >> 7;
    int m = b * 128 + mi;
    float s = 0.0f;
    for (int by = half; by < 64; by += 2) s += colp[(size_t)by * N_TOK + m];
    part[t] = s;
    __syncthreads();
    if (t < 128) lcolw[t] = part[t] + part[t + 128];
    __syncthreads();

    int c = mi;
    float aw = 0.0f, ah = 0.0f;
    for (int mm = half; mm < 128; mm += 2) {
        float h  = (float)h2b[(size_t)(b * 128 + mm) * D2 + c];
        float wv = lcolw[mm];
        aw += wv * h;
        ah += h;
    }
    atomicAdd(&xw[c], aw);
    atomicAdd(&xh[c], ah);
}

__global__ void logits_k(const float* __restrict__ xw, const float* __restrict__ xh,
                         const float* __restrict__ gamma, const float* __restrict__ W3,
                         const float* __restrict__ b3, float* __restrict__ out) {
    __shared__ float x2[D2];
    int t = threadIdx.x;
    float g = gamma[0];
    if (t < D2) x2[t] = (g * xw[t] + xh[t]) * (1.0f / (float)N_TOK);
    __syncthreads();
    if (t < 10) {
        float s = b3[t];
        for (int c = 0; c < D2; ++c) s += x2[c] * W3[t * D2 + c];
        out[t] = s;
    }
}

// ---------------------------------------------------------------------------
extern "C" void kernel_launch(void* const* d_in, const int* in_sizes, int n_in,
                              void* d_out, int out_size, void* d_ws, size_t ws_size,
                              hipStream_t stream) {
    const float* x     = (const float*)d_in[0];
    const float* W1    = (const float*)d_in[1];
    const float* b1    = (const float*)d_in[2];
    const float* W2    = (const float*)d_in[3];
    const float* b2    = (const float*)d_in[4];
    const float* Wq    = (const float*)d_in[5];
    const float* bq    = (const float*)d_in[6];
    const float* Wk    = (const float*)d_in[7];
    const float* bk    = (const float*)d_in[8];
    const float* gamma = (const float*)d_in[9];
    const float* W3    = (const float*)d_in[10];
    const float* b3    = (const float*)d_in[11];

    float* out  = (float*)d_out;
    float* attn = out + 10;            // 8192x8192 f32

    // workspace: round-7 layout (footprint <= round 7's passing 17.67 MB);
    // colp overlays h1b (8 MB, dead after mlp2) — overlay proven innocent
    // by round 9 (separate) vs round 10 (overlaid) identical results.
    char* p = (char*)d_ws;
    __bf16* w1b = (__bf16*)p; p += (size_t)D1 * IN_FEAT * 2;
    __bf16* w2b = (__bf16*)p; p += (size_t)D2 * D1 * 2;
    __bf16* wqb = (__bf16*)p; p += (size_t)D2 * D2 * 2;
    __bf16* h1b = (__bf16*)p; p += (size_t)N_TOK * D1 * 2;
    __bf16* h2b = (__bf16*)p; p += (size_t)N_TOK * D2 * 2;
    __bf16* qb  = (__bf16*)p; p += (size_t)N_TOK * D2 * 2;
    __bf16* kb  = (__bf16*)p; p += (size_t)N_TOK * D2 * 2;
    float* pm     = (float*)p; p += (size_t)2 * NKC * N_TOK * 4;   // 512 KB
    float* pl     = (float*)p; p += (size_t)2 * NKC * N_TOK * 4;   // 512 KB
    float* wksum  = (float*)p; p += D2 * 4;
    float* xw     = (float*)p; p += D2 * 4;
    float* xh     = (float*)p; p += D2 * 4;
    float* colp   = (float*)h1b;   // 2 MB, written by fa2 (h1b dead)

    prep<<<1105, 256, 0, stream>>>(W1, w1b, W2, w2b, Wq, wqb, Wk, wksum, xw, xh);

    gemm1_k<<<512, 256, 0, stream>>>(x, w1b, b1, h1b);
    mlp2_k<<<N_TOK / 32, 256, 0, stream>>>(h1b, w2b, b2, wqb, bq, wksum, bk, h2b, kb, qb);

    fa_kernel<1><<<dim3(NKC, NQB), 256, 0, stream>>>(qb, kb, pm, pl, nullptr, nullptr);
    fa_kernel<2><<<dim3(NKC, NQB), 256, 0, stream>>>(qb, kb, pm, pl, attn, colp);

    reduce_x2<<<64, 256, 0, stream>>>(h2b, colp, xw, xh);
    logits_k<<<1, 128, 0, stream>>>(xw, xh, gamma, W3, b3, out);
}